// Round 1
// 693.758 us; speedup vs baseline: 1.1959x; 1.1959x over previous
//
#include <hip/hip_runtime.h>
#include <hip/hip_bf16.h>

#define NPTS 16384
#define DIM  2048
#define NGRP 4096

typedef __bf16 bf16x8 __attribute__((ext_vector_type(8)));
typedef unsigned short u16x8 __attribute__((ext_vector_type(8)));
typedef float f32x4 __attribute__((ext_vector_type(4)));

__device__ __forceinline__ unsigned short f2bf(float f) {
  union { float f; unsigned u; } v; v.f = f;
  unsigned u = v.u;
  return (unsigned short)((u + 0x7FFFu + ((u >> 16) & 1u)) >> 16);  // round-to-nearest-even
}
__device__ __forceinline__ float bflo(unsigned u) { return __uint_as_float(u << 16); }
__device__ __forceinline__ float bfhi(unsigned u) { return __uint_as_float(u & 0xffff0000u); }

// Async global->LDS, 16B per lane. LDS dest is wave-uniform base + lane*16.
__device__ __forceinline__ void gload16(const void* g, void* lds) {
  __builtin_amdgcn_global_load_lds(
      (const __attribute__((address_space(1))) unsigned*)g,
      (__attribute__((address_space(3))) unsigned*)lds, 16, 0, 0);
}

// Decide whether inputs are bf16 (flag=1) or fp32 (flag=0) by inspecting bit
// patterns: for bf16 N(0,1) data ~99% of u16s have a sign+exponent-like high
// byte; for fp32 data only the odd u16s do (~50% overall). Deterministic.
__global__ void sniff_kernel(const unsigned short* __restrict__ X, int* __restrict__ flag) {
  if (threadIdx.x == 0 && blockIdx.x == 0) {
    int c = 0;
    for (int i = 0; i < 64; ++i) {
      unsigned b = (X[i] >> 8) & 0x7F;
      c += (b >= 0x3B && b <= 0x41) ? 1 : 0;
    }
    *flag = (c >= 48) ? 1 : 0;
  }
}

// Fused rownorm + fp32->bf16 conversion. One wave per row.
// bf16 input: compute norms only (GEMM will read the original buffer).
// fp32 input: compute norms AND write a bf16 copy to workspace (RTNE, same
// rounding as the previous in-loop f2bf -> bit-identical numerics).
__global__ __launch_bounds__(256) void prep_kernel(const void* __restrict__ in,
                                                   unsigned short* __restrict__ bf,
                                                   float* __restrict__ norms,
                                                   const int* __restrict__ flag) {
  const int wave = threadIdx.x >> 6;
  const int lane = threadIdx.x & 63;
  const int row  = blockIdx.x * 4 + wave;
  float s = 0.f;
  if (*flag) {
    const unsigned short* p = (const unsigned short*)in + (size_t)row * DIM;
#pragma unroll
    for (int it = 0; it < 4; ++it) {
      uint4 v = *(const uint4*)(p + it * 512 + lane * 8);
      float f;
      f = bflo(v.x); s += f * f;  f = bfhi(v.x); s += f * f;
      f = bflo(v.y); s += f * f;  f = bfhi(v.y); s += f * f;
      f = bflo(v.z); s += f * f;  f = bfhi(v.z); s += f * f;
      f = bflo(v.w); s += f * f;  f = bfhi(v.w); s += f * f;
    }
  } else {
    const float* p = (const float*)in + (size_t)row * DIM;
    unsigned short* q = bf + (size_t)row * DIM;
#pragma unroll
    for (int it = 0; it < 4; ++it) {
      float4 a = *(const float4*)(p + it * 512 + lane * 8);
      float4 b = *(const float4*)(p + it * 512 + lane * 8 + 4);
      s += a.x * a.x + a.y * a.y + a.z * a.z + a.w * a.w;
      s += b.x * b.x + b.y * b.y + b.z * b.z + b.w * b.w;
      u16x8 r;
      r[0] = f2bf(a.x); r[1] = f2bf(a.y); r[2] = f2bf(a.z); r[3] = f2bf(a.w);
      r[4] = f2bf(b.x); r[5] = f2bf(b.y); r[6] = f2bf(b.z); r[7] = f2bf(b.w);
      *(u16x8*)(q + it * 512 + lane * 8) = r;
    }
  }
#pragma unroll
  for (int off = 32; off > 0; off >>= 1) s += __shfl_down(s, off, 64);
  if (lane == 0) norms[row] = s;
}

// Fast GEMM: always consumes bf16 (original input if bf16, ws copy if fp32).
// m97 structure: 128x128 tile, BK=32, 4 waves x (4x4) 16x16x32 MFMA,
// global_load_lds_dwordx4 staging, 2 barriers per K-step.
__global__ __launch_bounds__(256) void gemm_fast_kernel(
    const void* __restrict__ Xin, const unsigned short* __restrict__ Xws,
    const void* __restrict__ Ein, const unsigned short* __restrict__ Ews,
    const float* __restrict__ x2, const float* __restrict__ e2,
    void* __restrict__ outv, const int* __restrict__ flag) {
  __shared__ __align__(16) unsigned short sA[128 * 32];
  __shared__ __align__(16) unsigned short sB[128 * 32];

  const bool isbf = (*flag != 0);
  const unsigned short* X = isbf ? (const unsigned short*)Xin : Xws;
  const unsigned short* E = isbf ? (const unsigned short*)Ein : Ews;

  const int tid  = threadIdx.x;
  const int lane = tid & 63;
  const int wave = tid >> 6;
  const int wm   = wave >> 1;
  const int wn   = wave & 1;
  const int quad = lane >> 4;
  const int l16  = lane & 15;

  const int rowBase = blockIdx.y * 128;
  const int colBase = blockIdx.x * 128;

  // Staging map (identical flat layout to previous kernel):
  // round 0 covers LDS elements [0,2048) = rows [0,64); round 1 = rows [64,128).
  const int r0 = tid >> 2;            // 0..63
  const int c0 = (tid & 3) * 8;       // 0..24

  const size_t iA0 = (size_t)(rowBase + r0) * DIM + c0;
  const size_t iA1 = iA0 + (size_t)64 * DIM;
  const size_t iB0 = (size_t)(colBase + r0) * DIM + c0;
  const size_t iB1 = iB0 + (size_t)64 * DIM;

  // Wave-uniform LDS bases: base + lane*16B == element tid*8 (round 0) / tid*8+2048 (round 1)
  unsigned short* dA0 = sA + wave * 512;
  unsigned short* dA1 = sA + 2048 + wave * 512;
  unsigned short* dB0 = sB + wave * 512;
  unsigned short* dB1 = sB + 2048 + wave * 512;

  f32x4 zero = {0.f, 0.f, 0.f, 0.f};
  f32x4 acc[4][4];
#pragma unroll
  for (int mt = 0; mt < 4; ++mt)
#pragma unroll
    for (int nt = 0; nt < 4; ++nt) acc[mt][nt] = zero;

  for (int k0 = 0; k0 < DIM; k0 += 32) {
    gload16(X + iA0 + k0, dA0);
    gload16(X + iA1 + k0, dA1);
    gload16(E + iB0 + k0, dB0);
    gload16(E + iB1 + k0, dB1);
    __syncthreads();  // compiler emits vmcnt(0) drain before barrier

    bf16x8 a[4], b[4];
#pragma unroll
    for (int mt = 0; mt < 4; ++mt)
      a[mt] = *(const bf16x8*)(const void*)(sA + (wm * 64 + mt * 16 + l16) * 32 + quad * 8);
#pragma unroll
    for (int nt = 0; nt < 4; ++nt)
      b[nt] = *(const bf16x8*)(const void*)(sB + (wn * 64 + nt * 16 + l16) * 32 + quad * 8);
#pragma unroll
    for (int mt = 0; mt < 4; ++mt)
#pragma unroll
      for (int nt = 0; nt < 4; ++nt)
        acc[mt][nt] = __builtin_amdgcn_mfma_f32_16x16x32_bf16(a[mt], b[nt], acc[mt][nt], 0, 0, 0);
    __syncthreads();
  }

  // C/D layout: col = lane&15, row = quad*4 + reg  [measured m89/m91]
  float ec[4];
#pragma unroll
  for (int nt = 0; nt < 4; ++nt) ec[nt] = e2[colBase + wn * 64 + nt * 16 + l16];

  if (isbf) {
    unsigned short* out = (unsigned short*)outv;
#pragma unroll
    for (int mt = 0; mt < 4; ++mt)
#pragma unroll
      for (int r = 0; r < 4; ++r) {
        const int row = rowBase + wm * 64 + mt * 16 + quad * 4 + r;
        const float xr = x2[row];
#pragma unroll
        for (int nt = 0; nt < 4; ++nt) {
          const int col = colBase + wn * 64 + nt * 16 + l16;
          float sq = xr + ec[nt] - 2.0f * acc[mt][nt][r];
          sq = sq > 0.f ? sq : 0.f;
          out[(size_t)row * NGRP + col] = f2bf(-__builtin_sqrtf(sq));
        }
      }
  } else {
    float* out = (float*)outv;
#pragma unroll
    for (int mt = 0; mt < 4; ++mt)
#pragma unroll
      for (int r = 0; r < 4; ++r) {
        const int row = rowBase + wm * 64 + mt * 16 + quad * 4 + r;
        const float xr = x2[row];
#pragma unroll
        for (int nt = 0; nt < 4; ++nt) {
          const int col = colBase + wn * 64 + nt * 16 + l16;
          float sq = xr + ec[nt] - 2.0f * acc[mt][nt][r];
          sq = sq > 0.f ? sq : 0.f;
          out[(size_t)row * NGRP + col] = -__builtin_sqrtf(sq);
        }
      }
  }
}

// ---------------- fallback path (workspace too small): previous kernel ----------------

__global__ __launch_bounds__(256) void rownorm_kernel(const void* __restrict__ in,
                                                      float* __restrict__ out,
                                                      const int* __restrict__ flag) {
  const int wave = threadIdx.x >> 6;
  const int lane = threadIdx.x & 63;
  const int row  = blockIdx.x * 4 + wave;
  float s = 0.f;
  if (*flag) {
    const unsigned short* p = (const unsigned short*)in + (size_t)row * DIM;
#pragma unroll
    for (int it = 0; it < 4; ++it) {
      uint4 v = *(const uint4*)(p + it * 512 + lane * 8);
      float f;
      f = bflo(v.x); s += f * f;  f = bfhi(v.x); s += f * f;
      f = bflo(v.y); s += f * f;  f = bfhi(v.y); s += f * f;
      f = bflo(v.z); s += f * f;  f = bfhi(v.z); s += f * f;
      f = bflo(v.w); s += f * f;  f = bfhi(v.w); s += f * f;
    }
  } else {
    const float* p = (const float*)in + (size_t)row * DIM;
#pragma unroll
    for (int it = 0; it < 4; ++it) {
      float4 a = *(const float4*)(p + it * 512 + lane * 8);
      float4 b = *(const float4*)(p + it * 512 + lane * 8 + 4);
      s += a.x * a.x + a.y * a.y + a.z * a.z + a.w * a.w;
      s += b.x * b.x + b.y * b.y + b.z * b.z + b.w * b.w;
    }
  }
#pragma unroll
  for (int off = 32; off > 0; off >>= 1) s += __shfl_down(s, off, 64);
  if (lane == 0) out[row] = s;
}

__device__ __forceinline__ u16x8 cvt8(const float* p) {
  float4 a = *(const float4*)p;
  float4 b = *(const float4*)(p + 4);
  u16x8 r;
  r[0] = f2bf(a.x); r[1] = f2bf(a.y); r[2] = f2bf(a.z); r[3] = f2bf(a.w);
  r[4] = f2bf(b.x); r[5] = f2bf(b.y); r[6] = f2bf(b.z); r[7] = f2bf(b.w);
  return r;
}

__global__ __launch_bounds__(256) void gemm_dist_kernel(
    const void* __restrict__ Xv, const void* __restrict__ Ev,
    const float* __restrict__ x2, const float* __restrict__ e2,
    void* __restrict__ outv, const int* __restrict__ flag) {
  __shared__ __align__(16) unsigned short sA[128 * 32];
  __shared__ __align__(16) unsigned short sB[128 * 32];

  const bool isbf = (*flag != 0);
  const int tid  = threadIdx.x;
  const int lane = tid & 63;
  const int wave = tid >> 6;
  const int wm   = wave >> 1;
  const int wn   = wave & 1;
  const int quad = lane >> 4;
  const int l16  = lane & 15;

  const int rowBase = blockIdx.y * 128;
  const int colBase = blockIdx.x * 128;

  const int flat0 = tid * 8;
  const int flat1 = (tid + 256) * 8;
  const int r0 = flat0 >> 5, c0 = flat0 & 31;
  const int r1 = flat1 >> 5, c1 = flat1 & 31;

  const size_t iA0 = (size_t)(rowBase + r0) * DIM + c0;
  const size_t iA1 = (size_t)(rowBase + r1) * DIM + c1;
  const size_t iB0 = (size_t)(colBase + r0) * DIM + c0;
  const size_t iB1 = (size_t)(colBase + r1) * DIM + c1;

  f32x4 zero = {0.f, 0.f, 0.f, 0.f};
  f32x4 acc[4][4];
#pragma unroll
  for (int mt = 0; mt < 4; ++mt)
#pragma unroll
    for (int nt = 0; nt < 4; ++nt) acc[mt][nt] = zero;

  for (int k0 = 0; k0 < DIM; k0 += 32) {
    if (isbf) {
      const unsigned short* X = (const unsigned short*)Xv;
      const unsigned short* E = (const unsigned short*)Ev;
      *(uint4*)(sA + flat0) = *(const uint4*)(X + iA0 + k0);
      *(uint4*)(sA + flat1) = *(const uint4*)(X + iA1 + k0);
      *(uint4*)(sB + flat0) = *(const uint4*)(E + iB0 + k0);
      *(uint4*)(sB + flat1) = *(const uint4*)(E + iB1 + k0);
    } else {
      const float* X = (const float*)Xv;
      const float* E = (const float*)Ev;
      *(u16x8*)(sA + flat0) = cvt8(X + iA0 + k0);
      *(u16x8*)(sA + flat1) = cvt8(X + iA1 + k0);
      *(u16x8*)(sB + flat0) = cvt8(E + iB0 + k0);
      *(u16x8*)(sB + flat1) = cvt8(E + iB1 + k0);
    }
    __syncthreads();

    bf16x8 a[4], b[4];
#pragma unroll
    for (int mt = 0; mt < 4; ++mt)
      a[mt] = *(const bf16x8*)(const void*)(sA + (wm * 64 + mt * 16 + l16) * 32 + quad * 8);
#pragma unroll
    for (int nt = 0; nt < 4; ++nt)
      b[nt] = *(const bf16x8*)(const void*)(sB + (wn * 64 + nt * 16 + l16) * 32 + quad * 8);
#pragma unroll
    for (int mt = 0; mt < 4; ++mt)
#pragma unroll
      for (int nt = 0; nt < 4; ++nt)
        acc[mt][nt] = __builtin_amdgcn_mfma_f32_16x16x32_bf16(a[mt], b[nt], acc[mt][nt], 0, 0, 0);
    __syncthreads();
  }

  float ec[4];
#pragma unroll
  for (int nt = 0; nt < 4; ++nt) ec[nt] = e2[colBase + wn * 64 + nt * 16 + l16];

  if (isbf) {
    unsigned short* out = (unsigned short*)outv;
#pragma unroll
    for (int mt = 0; mt < 4; ++mt)
#pragma unroll
      for (int r = 0; r < 4; ++r) {
        const int row = rowBase + wm * 64 + mt * 16 + quad * 4 + r;
        const float xr = x2[row];
#pragma unroll
        for (int nt = 0; nt < 4; ++nt) {
          const int col = colBase + wn * 64 + nt * 16 + l16;
          float sq = xr + ec[nt] - 2.0f * acc[mt][nt][r];
          sq = sq > 0.f ? sq : 0.f;
          out[(size_t)row * NGRP + col] = f2bf(-__builtin_sqrtf(sq));
        }
      }
  } else {
    float* out = (float*)outv;
#pragma unroll
    for (int mt = 0; mt < 4; ++mt)
#pragma unroll
      for (int r = 0; r < 4; ++r) {
        const int row = rowBase + wm * 64 + mt * 16 + quad * 4 + r;
        const float xr = x2[row];
#pragma unroll
        for (int nt = 0; nt < 4; ++nt) {
          const int col = colBase + wn * 64 + nt * 16 + l16;
          float sq = xr + ec[nt] - 2.0f * acc[mt][nt][r];
          sq = sq > 0.f ? sq : 0.f;
          out[(size_t)row * NGRP + col] = -__builtin_sqrtf(sq);
        }
      }
  }
}

extern "C" void kernel_launch(void* const* d_in, const int* in_sizes, int n_in,
                              void* d_out, int out_size, void* d_ws, size_t ws_size,
                              hipStream_t stream) {
  const size_t xbf = (size_t)NPTS * DIM;
  const size_t ebf = (size_t)NGRP * DIM;
  const size_t need = (xbf + ebf) * sizeof(unsigned short)
                    + (NPTS + NGRP) * sizeof(float) + 64;

  if (ws_size >= need) {
    // Fast path: bf16 workspace copies + global_load_lds GEMM.
    unsigned short* Xbf = (unsigned short*)d_ws;
    unsigned short* Ebf = Xbf + xbf;
    float* x2 = (float*)(Ebf + ebf);
    float* e2 = x2 + NPTS;
    int* flag = (int*)(e2 + NGRP);

    sniff_kernel<<<1, 64, 0, stream>>>((const unsigned short*)d_in[0], flag);
    prep_kernel<<<NPTS / 4, 256, 0, stream>>>(d_in[0], Xbf, x2, flag);
    prep_kernel<<<NGRP / 4, 256, 0, stream>>>(d_in[1], Ebf, e2, flag);
    dim3 grid(NGRP / 128, NPTS / 128);
    gemm_fast_kernel<<<grid, 256, 0, stream>>>(d_in[0], Xbf, d_in[1], Ebf,
                                               x2, e2, d_out, flag);
  } else {
    // Fallback: previous verified path (in-loop conversion staging).
    float* x2 = (float*)d_ws;
    float* e2 = x2 + NPTS;
    int* flag = (int*)(e2 + NGRP);

    sniff_kernel<<<1, 64, 0, stream>>>((const unsigned short*)d_in[0], flag);
    rownorm_kernel<<<NPTS / 4, 256, 0, stream>>>(d_in[0], x2, flag);
    rownorm_kernel<<<NGRP / 4, 256, 0, stream>>>(d_in[1], e2, flag);
    dim3 grid(NGRP / 128, NPTS / 128);
    gemm_dist_kernel<<<grid, 256, 0, stream>>>(d_in[0], d_in[1], x2, e2, d_out, flag);
  }
}

// Round 2
// 679.185 us; speedup vs baseline: 1.2215x; 1.0215x over previous
//
#include <hip/hip_runtime.h>
#include <hip/hip_bf16.h>

#define NPTS 16384
#define DIM  2048
#define NGRP 4096
#define BK   32
#define NT   (DIM / BK)   // 64 K-tiles

typedef __bf16 bf16x8 __attribute__((ext_vector_type(8)));
typedef unsigned short u16x8 __attribute__((ext_vector_type(8)));
typedef float f32x4 __attribute__((ext_vector_type(4)));

__device__ __forceinline__ unsigned short f2bf(float f) {
  union { float f; unsigned u; } v; v.f = f;
  unsigned u = v.u;
  return (unsigned short)((u + 0x7FFFu + ((u >> 16) & 1u)) >> 16);  // RTNE
}
__device__ __forceinline__ float bflo(unsigned u) { return __uint_as_float(u << 16); }
__device__ __forceinline__ float bfhi(unsigned u) { return __uint_as_float(u & 0xffff0000u); }

// Async global->LDS, 16B per lane. LDS dest is wave-uniform base + lane*16.
__device__ __forceinline__ void gload16(const void* g, void* lds) {
  __builtin_amdgcn_global_load_lds(
      (const __attribute__((address_space(1))) unsigned*)g,
      (__attribute__((address_space(3))) unsigned*)lds, 16, 0, 0);
}

// Per-wave deterministic dtype sniff: all waves inspect X[0..63] -> identical verdict.
__device__ __forceinline__ bool sniff_bf16(const void* X) {
  const int lane = threadIdx.x & 63;
  unsigned hb = (((const unsigned short*)X)[lane] >> 8) & 0x7Fu;
  unsigned long long m = __ballot(hb >= 0x3Bu && hb <= 0x41u);
  return __popcll(m) >= 48;
}

// ---- fused prep: self-sniff + row norms (+ fp32->bf16 copy when fp32 input) ----
__global__ __launch_bounds__(256) void prep_all_kernel(
    const void* __restrict__ Xin, const void* __restrict__ Ein,
    unsigned short* __restrict__ Xbf, unsigned short* __restrict__ Ebf,
    float* __restrict__ x2, float* __restrict__ e2) {
  const int lane  = threadIdx.x & 63;
  const int wavei = threadIdx.x >> 6;
  const bool isbf = sniff_bf16(Xin);

  const int grow = blockIdx.x * 4 + wavei;
  const void* in; unsigned short* q; float* nrm; int row;
  if (grow < NPTS) { in = Xin; q = Xbf; nrm = x2; row = grow; }
  else             { in = Ein; q = Ebf; nrm = e2; row = grow - NPTS; }

  float s = 0.f;
  if (isbf) {
    const unsigned short* p = (const unsigned short*)in + (size_t)row * DIM;
#pragma unroll
    for (int it = 0; it < 4; ++it) {
      uint4 v = *(const uint4*)(p + it * 512 + lane * 8);
      float f;
      f = bflo(v.x); s += f * f;  f = bfhi(v.x); s += f * f;
      f = bflo(v.y); s += f * f;  f = bfhi(v.y); s += f * f;
      f = bflo(v.z); s += f * f;  f = bfhi(v.z); s += f * f;
      f = bflo(v.w); s += f * f;  f = bfhi(v.w); s += f * f;
    }
  } else {
    const float* p = (const float*)in + (size_t)row * DIM;
    unsigned short* qq = q + (size_t)row * DIM;
#pragma unroll
    for (int it = 0; it < 4; ++it) {
      float4 a = *(const float4*)(p + it * 512 + lane * 8);
      float4 b = *(const float4*)(p + it * 512 + lane * 8 + 4);
      s += a.x * a.x + a.y * a.y + a.z * a.z + a.w * a.w;
      s += b.x * b.x + b.y * b.y + b.z * b.z + b.w * b.w;
      u16x8 r;
      r[0] = f2bf(a.x); r[1] = f2bf(a.y); r[2] = f2bf(a.z); r[3] = f2bf(a.w);
      r[4] = f2bf(b.x); r[5] = f2bf(b.y); r[6] = f2bf(b.z); r[7] = f2bf(b.w);
      *(u16x8*)(qq + it * 512 + lane * 8) = r;
    }
  }
#pragma unroll
  for (int off = 32; off > 0; off >>= 1) s += __shfl_down(s, off, 64);
  if (lane == 0) nrm[row] = s;
}

// ---- pipelined GEMM: 128x128 tile, BK=32, 3-deep circular LDS buffer,
//      counted vmcnt (never 0 in main loop), XOR-swizzled LDS, setprio MFMA ----
__global__ __launch_bounds__(256) void gemm_pipe_kernel(
    const void* __restrict__ Xin, const unsigned short* __restrict__ Xws,
    const void* __restrict__ Ein, const unsigned short* __restrict__ Ews,
    const float* __restrict__ x2, const float* __restrict__ e2,
    void* __restrict__ outv) {
  // [buf][ A: 0..4096 | B: 4096..8192 ] elems; 3 x 16 KB = 48 KB
  __shared__ __align__(16) unsigned short sbuf[3][8192];

  const int tid  = threadIdx.x;
  const int lane = tid & 63;
  const int wave = tid >> 6;
  const int wm   = wave >> 1;
  const int wn   = wave & 1;
  const int quad = lane >> 4;
  const int l16  = lane & 15;

  const bool isbf = sniff_bf16(Xin);
  const unsigned short* X = isbf ? (const unsigned short*)Xin : Xws;
  const unsigned short* E = isbf ? (const unsigned short*)Ein : Ews;

  const int rowBase = blockIdx.y * 128;
  const int colBase = blockIdx.x * 128;

  // Staging: thread t, round r covers LDS elems (r*256+t)*8 .. +8 (linear dest).
  // Swizzle (rule #21: linear dest + inverse-swizzled SOURCE): row = (r*256+t)>>2,
  // source col = ((t&3) ^ (row&3)) * 8.  (row&3) == ((t>>2)&3) for both rounds.
  const int srow = tid >> 2;                          // 0..63 (round 1 adds 64)
  const int scol = ((tid & 3) ^ (srow & 3)) * 8;
  const size_t gA0 = (size_t)(rowBase + srow) * DIM + scol;
  const size_t gA1 = gA0 + (size_t)64 * DIM;
  const size_t gB0 = (size_t)(colBase + srow) * DIM + scol;
  const size_t gB1 = gB0 + (size_t)64 * DIM;

  // Fragment ds_read with matching swizzle: elem = row*32 + ((quad ^ (row&3))*8),
  // row = (wm*64 + mt*16 + l16) -> row&3 == l16&3.
  const int kc    = (quad ^ (l16 & 3)) * 8;
  const int aoff0 = (wm * 64 + l16) * 32 + kc;        // + mt*512
  const int boff0 = 4096 + (wn * 64 + l16) * 32 + kc; // + nt*512

  f32x4 zero = {0.f, 0.f, 0.f, 0.f};
  f32x4 acc[4][4];
#pragma unroll
  for (int mt = 0; mt < 4; ++mt)
#pragma unroll
    for (int nt = 0; nt < 4; ++nt) acc[mt][nt] = zero;

#define STAGE(t_, bi_) do {                                   \
    const int k0_ = (t_) * BK;                                \
    gload16(X + gA0 + k0_, &sbuf[bi_][wave * 512]);           \
    gload16(X + gA1 + k0_, &sbuf[bi_][2048 + wave * 512]);    \
    gload16(E + gB0 + k0_, &sbuf[bi_][4096 + wave * 512]);    \
    gload16(E + gB1 + k0_, &sbuf[bi_][6144 + wave * 512]);    \
  } while (0)

#define COMPUTE(bi_) do {                                                        \
    const unsigned short* sb_ = sbuf[bi_];                                       \
    bf16x8 af_[4], bf_[4];                                                       \
    _Pragma("unroll") for (int mt = 0; mt < 4; ++mt)                             \
      af_[mt] = *(const bf16x8*)(const void*)(sb_ + aoff0 + mt * 512);           \
    _Pragma("unroll") for (int nt = 0; nt < 4; ++nt)                             \
      bf_[nt] = *(const bf16x8*)(const void*)(sb_ + boff0 + nt * 512);           \
    __builtin_amdgcn_s_setprio(1);                                               \
    _Pragma("unroll") for (int mt = 0; mt < 4; ++mt)                             \
      _Pragma("unroll") for (int nt = 0; nt < 4; ++nt)                           \
        acc[mt][nt] = __builtin_amdgcn_mfma_f32_16x16x32_bf16(af_[mt], bf_[nt],  \
                                                              acc[mt][nt], 0, 0, 0); \
    __builtin_amdgcn_s_setprio(0);                                               \
  } while (0)

  // Prologue: 3 tiles in flight (12 loads/thread).
  STAGE(0, 0); STAGE(1, 1); STAGE(2, 2);

  int bi = 0;
  for (int t = 0; t < NT - 3; ++t) {
    asm volatile("s_waitcnt vmcnt(8)" ::: "memory");   // tile t landed; t+1,t+2 in flight
    __builtin_amdgcn_s_barrier();                      // everyone's tile-t stores visible
    __builtin_amdgcn_sched_barrier(0);
    COMPUTE(bi);
    __builtin_amdgcn_s_barrier();                      // all waves done reading buf bi
    __builtin_amdgcn_sched_barrier(0);
    STAGE(t + 3, bi);                                  // refill freed buffer
    bi = (bi == 2) ? 0 : bi + 1;
  }
  // Tail: drain 8 -> 4 -> 0 (template epilogue rule).
  asm volatile("s_waitcnt vmcnt(8)" ::: "memory");
  __builtin_amdgcn_s_barrier();
  __builtin_amdgcn_sched_barrier(0);
  COMPUTE(bi);                                         // t = NT-3
  bi = (bi == 2) ? 0 : bi + 1;
  asm volatile("s_waitcnt vmcnt(4)" ::: "memory");
  __builtin_amdgcn_s_barrier();
  __builtin_amdgcn_sched_barrier(0);
  COMPUTE(bi);                                         // t = NT-2
  bi = (bi == 2) ? 0 : bi + 1;
  asm volatile("s_waitcnt vmcnt(0)" ::: "memory");
  __builtin_amdgcn_s_barrier();
  __builtin_amdgcn_sched_barrier(0);
  COMPUTE(bi);                                         // t = NT-1
#undef STAGE
#undef COMPUTE

  // Epilogue. C/D layout: col = lane&15, row = quad*4 + reg [m89/m91].
  float ec[4];
#pragma unroll
  for (int nt = 0; nt < 4; ++nt) ec[nt] = e2[colBase + wn * 64 + nt * 16 + l16];

  if (isbf) {
    unsigned short* out = (unsigned short*)outv;
#pragma unroll
    for (int mt = 0; mt < 4; ++mt)
#pragma unroll
      for (int r = 0; r < 4; ++r) {
        const int row = rowBase + wm * 64 + mt * 16 + quad * 4 + r;
        const float xr = x2[row];
#pragma unroll
        for (int nt = 0; nt < 4; ++nt) {
          const int col = colBase + wn * 64 + nt * 16 + l16;
          float sq = xr + ec[nt] - 2.0f * acc[mt][nt][r];
          sq = sq > 0.f ? sq : 0.f;
          out[(size_t)row * NGRP + col] = f2bf(-__builtin_sqrtf(sq));
        }
      }
  } else {
    float* out = (float*)outv;
#pragma unroll
    for (int mt = 0; mt < 4; ++mt)
#pragma unroll
      for (int r = 0; r < 4; ++r) {
        const int row = rowBase + wm * 64 + mt * 16 + quad * 4 + r;
        const float xr = x2[row];
#pragma unroll
        for (int nt = 0; nt < 4; ++nt) {
          const int col = colBase + wn * 64 + nt * 16 + l16;
          float sq = xr + ec[nt] - 2.0f * acc[mt][nt][r];
          sq = sq > 0.f ? sq : 0.f;
          out[(size_t)row * NGRP + col] = -__builtin_sqrtf(sq);
        }
      }
  }
}

// ---------------- fallback path (workspace too small): round-0 kernels ----------------

__global__ void sniff_kernel(const unsigned short* __restrict__ X, int* __restrict__ flag) {
  if (threadIdx.x == 0 && blockIdx.x == 0) {
    int c = 0;
    for (int i = 0; i < 64; ++i) {
      unsigned b = (X[i] >> 8) & 0x7F;
      c += (b >= 0x3B && b <= 0x41) ? 1 : 0;
    }
    *flag = (c >= 48) ? 1 : 0;
  }
}

__global__ __launch_bounds__(256) void rownorm_kernel(const void* __restrict__ in,
                                                      float* __restrict__ out,
                                                      const int* __restrict__ flag) {
  const int wave = threadIdx.x >> 6;
  const int lane = threadIdx.x & 63;
  const int row  = blockIdx.x * 4 + wave;
  float s = 0.f;
  if (*flag) {
    const unsigned short* p = (const unsigned short*)in + (size_t)row * DIM;
#pragma unroll
    for (int it = 0; it < 4; ++it) {
      uint4 v = *(const uint4*)(p + it * 512 + lane * 8);
      float f;
      f = bflo(v.x); s += f * f;  f = bfhi(v.x); s += f * f;
      f = bflo(v.y); s += f * f;  f = bfhi(v.y); s += f * f;
      f = bflo(v.z); s += f * f;  f = bfhi(v.z); s += f * f;
      f = bflo(v.w); s += f * f;  f = bfhi(v.w); s += f * f;
    }
  } else {
    const float* p = (const float*)in + (size_t)row * DIM;
#pragma unroll
    for (int it = 0; it < 4; ++it) {
      float4 a = *(const float4*)(p + it * 512 + lane * 8);
      float4 b = *(const float4*)(p + it * 512 + lane * 8 + 4);
      s += a.x * a.x + a.y * a.y + a.z * a.z + a.w * a.w;
      s += b.x * b.x + b.y * b.y + b.z * b.z + b.w * b.w;
    }
  }
#pragma unroll
  for (int off = 32; off > 0; off >>= 1) s += __shfl_down(s, off, 64);
  if (lane == 0) out[row] = s;
}

__device__ __forceinline__ u16x8 cvt8(const float* p) {
  float4 a = *(const float4*)p;
  float4 b = *(const float4*)(p + 4);
  u16x8 r;
  r[0] = f2bf(a.x); r[1] = f2bf(a.y); r[2] = f2bf(a.z); r[3] = f2bf(a.w);
  r[4] = f2bf(b.x); r[5] = f2bf(b.y); r[6] = f2bf(b.z); r[7] = f2bf(b.w);
  return r;
}

__global__ __launch_bounds__(256) void gemm_dist_kernel(
    const void* __restrict__ Xv, const void* __restrict__ Ev,
    const float* __restrict__ x2, const float* __restrict__ e2,
    void* __restrict__ outv, const int* __restrict__ flag) {
  __shared__ __align__(16) unsigned short sA[128 * 32];
  __shared__ __align__(16) unsigned short sB[128 * 32];

  const bool isbf = (*flag != 0);
  const int tid  = threadIdx.x;
  const int lane = tid & 63;
  const int wave = tid >> 6;
  const int wm   = wave >> 1;
  const int wn   = wave & 1;
  const int quad = lane >> 4;
  const int l16  = lane & 15;

  const int rowBase = blockIdx.y * 128;
  const int colBase = blockIdx.x * 128;

  const int flat0 = tid * 8;
  const int flat1 = (tid + 256) * 8;
  const int r0 = flat0 >> 5, c0 = flat0 & 31;
  const int r1 = flat1 >> 5, c1 = flat1 & 31;

  const size_t iA0 = (size_t)(rowBase + r0) * DIM + c0;
  const size_t iA1 = (size_t)(rowBase + r1) * DIM + c1;
  const size_t iB0 = (size_t)(colBase + r0) * DIM + c0;
  const size_t iB1 = (size_t)(colBase + r1) * DIM + c1;

  f32x4 zero = {0.f, 0.f, 0.f, 0.f};
  f32x4 acc[4][4];
#pragma unroll
  for (int mt = 0; mt < 4; ++mt)
#pragma unroll
    for (int nt = 0; nt < 4; ++nt) acc[mt][nt] = zero;

  for (int k0 = 0; k0 < DIM; k0 += 32) {
    if (isbf) {
      const unsigned short* X = (const unsigned short*)Xv;
      const unsigned short* E = (const unsigned short*)Ev;
      *(uint4*)(sA + flat0) = *(const uint4*)(X + iA0 + k0);
      *(uint4*)(sA + flat1) = *(const uint4*)(X + iA1 + k0);
      *(uint4*)(sB + flat0) = *(const uint4*)(E + iB0 + k0);
      *(uint4*)(sB + flat1) = *(const uint4*)(E + iB1 + k0);
    } else {
      const float* X = (const float*)Xv;
      const float* E = (const float*)Ev;
      *(u16x8*)(sA + flat0) = cvt8(X + iA0 + k0);
      *(u16x8*)(sA + flat1) = cvt8(X + iA1 + k0);
      *(u16x8*)(sB + flat0) = cvt8(E + iB0 + k0);
      *(u16x8*)(sB + flat1) = cvt8(E + iB1 + k0);
    }
    __syncthreads();

    bf16x8 a[4], b[4];
#pragma unroll
    for (int mt = 0; mt < 4; ++mt)
      a[mt] = *(const bf16x8*)(const void*)(sA + (wm * 64 + mt * 16 + l16) * 32 + quad * 8);
#pragma unroll
    for (int nt = 0; nt < 4; ++nt)
      b[nt] = *(const bf16x8*)(const void*)(sB + (wn * 64 + nt * 16 + l16) * 32 + quad * 8);
#pragma unroll
    for (int mt = 0; mt < 4; ++mt)
#pragma unroll
      for (int nt = 0; nt < 4; ++nt)
        acc[mt][nt] = __builtin_amdgcn_mfma_f32_16x16x32_bf16(a[mt], b[nt], acc[mt][nt], 0, 0, 0);
    __syncthreads();
  }

  float ec[4];
#pragma unroll
  for (int nt = 0; nt < 4; ++nt) ec[nt] = e2[colBase + wn * 64 + nt * 16 + l16];

  if (isbf) {
    unsigned short* out = (unsigned short*)outv;
#pragma unroll
    for (int mt = 0; mt < 4; ++mt)
#pragma unroll
      for (int r = 0; r < 4; ++r) {
        const int row = rowBase + wm * 64 + mt * 16 + quad * 4 + r;
        const float xr = x2[row];
#pragma unroll
        for (int nt = 0; nt < 4; ++nt) {
          const int col = colBase + wn * 64 + nt * 16 + l16;
          float sq = xr + ec[nt] - 2.0f * acc[mt][nt][r];
          sq = sq > 0.f ? sq : 0.f;
          out[(size_t)row * NGRP + col] = f2bf(-__builtin_sqrtf(sq));
        }
      }
  } else {
    float* out = (float*)outv;
#pragma unroll
    for (int mt = 0; mt < 4; ++mt)
#pragma unroll
      for (int r = 0; r < 4; ++r) {
        const int row = rowBase + wm * 64 + mt * 16 + quad * 4 + r;
        const float xr = x2[row];
#pragma unroll
        for (int nt = 0; nt < 4; ++nt) {
          const int col = colBase + wn * 64 + nt * 16 + l16;
          float sq = xr + ec[nt] - 2.0f * acc[mt][nt][r];
          sq = sq > 0.f ? sq : 0.f;
          out[(size_t)row * NGRP + col] = -__builtin_sqrtf(sq);
        }
      }
  }
}

extern "C" void kernel_launch(void* const* d_in, const int* in_sizes, int n_in,
                              void* d_out, int out_size, void* d_ws, size_t ws_size,
                              hipStream_t stream) {
  const size_t xbf = (size_t)NPTS * DIM;
  const size_t ebf = (size_t)NGRP * DIM;
  const size_t need = (xbf + ebf) * sizeof(unsigned short)
                    + (NPTS + NGRP) * sizeof(float) + 64;

  if (ws_size >= need) {
    // Fast path: 2 launches. Fused prep (self-sniff) + pipelined GEMM (self-sniff).
    unsigned short* Xbf = (unsigned short*)d_ws;
    unsigned short* Ebf = Xbf + xbf;
    float* x2 = (float*)(Ebf + ebf);
    float* e2 = x2 + NPTS;

    prep_all_kernel<<<(NPTS + NGRP) / 4, 256, 0, stream>>>(d_in[0], d_in[1],
                                                           Xbf, Ebf, x2, e2);
    dim3 grid(NGRP / 128, NPTS / 128);
    gemm_pipe_kernel<<<grid, 256, 0, stream>>>(d_in[0], Xbf, d_in[1], Ebf,
                                               x2, e2, d_out);
  } else {
    // Fallback: round-0 verified path.
    float* x2 = (float*)d_ws;
    float* e2 = x2 + NPTS;
    int* flag = (int*)(e2 + NGRP);

    sniff_kernel<<<1, 64, 0, stream>>>((const unsigned short*)d_in[0], flag);
    rownorm_kernel<<<NPTS / 4, 256, 0, stream>>>(d_in[0], x2, flag);
    rownorm_kernel<<<NGRP / 4, 256, 0, stream>>>(d_in[1], e2, flag);
    dim3 grid(NGRP / 128, NPTS / 128);
    gemm_dist_kernel<<<grid, 256, 0, stream>>>(d_in[0], d_in[1], x2, e2, d_out, flag);
  }
}

// Round 3
// 633.967 us; speedup vs baseline: 1.3087x; 1.0713x over previous
//
#include <hip/hip_runtime.h>
#include <hip/hip_bf16.h>

#define NPTS 16384
#define DIM  2048
#define NGRP 4096
#define BK   32
#define NT   (DIM / BK)   // 64 K-tiles

typedef __bf16 bf16x8 __attribute__((ext_vector_type(8)));
typedef unsigned short u16x8 __attribute__((ext_vector_type(8)));
typedef float f32x4 __attribute__((ext_vector_type(4)));

__device__ __forceinline__ unsigned short f2bf(float f) {
  union { float f; unsigned u; } v; v.f = f;
  unsigned u = v.u;
  return (unsigned short)((u + 0x7FFFu + ((u >> 16) & 1u)) >> 16);  // RTNE
}
__device__ __forceinline__ float bflo(unsigned u) { return __uint_as_float(u << 16); }
__device__ __forceinline__ float bfhi(unsigned u) { return __uint_as_float(u & 0xffff0000u); }

// Async global->LDS, 16B per lane. LDS dest is wave-uniform base + lane*16.
__device__ __forceinline__ void gload16(const void* g, void* lds) {
  __builtin_amdgcn_global_load_lds(
      (const __attribute__((address_space(1))) unsigned*)g,
      (__attribute__((address_space(3))) unsigned*)lds, 16, 0, 0);
}

// Per-wave deterministic dtype sniff: all waves inspect X[0..63] -> identical verdict.
__device__ __forceinline__ bool sniff_bf16(const void* X) {
  const int lane = threadIdx.x & 63;
  unsigned hb = (((const unsigned short*)X)[lane] >> 8) & 0x7Fu;
  unsigned long long m = __ballot(hb >= 0x3Bu && hb <= 0x41u);
  return __popcll(m) >= 48;
}

// ---- fused prep: self-sniff + row norms (+ fp32->bf16 copy when fp32 input) ----
__global__ __launch_bounds__(256) void prep_all_kernel(
    const void* __restrict__ Xin, const void* __restrict__ Ein,
    unsigned short* __restrict__ Xbf, unsigned short* __restrict__ Ebf,
    float* __restrict__ x2, float* __restrict__ e2) {
  const int lane  = threadIdx.x & 63;
  const int wavei = threadIdx.x >> 6;
  const bool isbf = sniff_bf16(Xin);

  const int grow = blockIdx.x * 4 + wavei;
  const void* in; unsigned short* q; float* nrm; int row;
  if (grow < NPTS) { in = Xin; q = Xbf; nrm = x2; row = grow; }
  else             { in = Ein; q = Ebf; nrm = e2; row = grow - NPTS; }

  float s = 0.f;
  if (isbf) {
    const unsigned short* p = (const unsigned short*)in + (size_t)row * DIM;
#pragma unroll
    for (int it = 0; it < 4; ++it) {
      uint4 v = *(const uint4*)(p + it * 512 + lane * 8);
      float f;
      f = bflo(v.x); s += f * f;  f = bfhi(v.x); s += f * f;
      f = bflo(v.y); s += f * f;  f = bfhi(v.y); s += f * f;
      f = bflo(v.z); s += f * f;  f = bfhi(v.z); s += f * f;
      f = bflo(v.w); s += f * f;  f = bfhi(v.w); s += f * f;
    }
  } else {
    const float* p = (const float*)in + (size_t)row * DIM;
    unsigned short* qq = q + (size_t)row * DIM;
#pragma unroll
    for (int it = 0; it < 4; ++it) {
      float4 a = *(const float4*)(p + it * 512 + lane * 8);
      float4 b = *(const float4*)(p + it * 512 + lane * 8 + 4);
      s += a.x * a.x + a.y * a.y + a.z * a.z + a.w * a.w;
      s += b.x * b.x + b.y * b.y + b.z * b.z + b.w * b.w;
      u16x8 r;
      r[0] = f2bf(a.x); r[1] = f2bf(a.y); r[2] = f2bf(a.z); r[3] = f2bf(a.w);
      r[4] = f2bf(b.x); r[5] = f2bf(b.y); r[6] = f2bf(b.z); r[7] = f2bf(b.w);
      *(u16x8*)(qq + it * 512 + lane * 8) = r;
    }
  }
#pragma unroll
  for (int off = 32; off > 0; off >>= 1) s += __shfl_down(s, off, 64);
  if (lane == 0) nrm[row] = s;
}

// ---- 256x256 8-wave GEMM, BK=32, 4-deep circular LDS (128 KiB), 2 fine phases
//      per K-tile {ds_read || global_load_lds || 16 MFMA}, counted vmcnt(8),
//      raw barriers (no vmcnt-0 drain), setprio around MFMA clusters ----
#define A_OFF 0
#define B_OFF 8192

__global__ __launch_bounds__(512, 2) void gemm_8p_kernel(
    const void* __restrict__ Xin, const unsigned short* __restrict__ Xws,
    const void* __restrict__ Ein, const unsigned short* __restrict__ Ews,
    const float* __restrict__ x2, const float* __restrict__ e2,
    void* __restrict__ outv) {
  // 4 bufs x [ A: 256x32 | B: 256x32 ] bf16 = 4 x 32 KiB = 128 KiB
  __shared__ __align__(16) unsigned short sbuf[4][16384];

  const int tid  = threadIdx.x;
  const int lane = tid & 63;
  const int wave = tid >> 6;   // 0..7
  const int wm   = wave >> 2;  // 0..1  (M half: 128 rows)
  const int wn   = wave & 3;   // 0..3  (N quarter: 64 cols)
  const int quad = lane >> 4;
  const int l16  = lane & 15;

  const bool isbf = sniff_bf16(Xin);
  const unsigned short* X = isbf ? (const unsigned short*)Xin : Xws;
  const unsigned short* E = isbf ? (const unsigned short*)Ein : Ews;

  const int rowBase = blockIdx.y * 256;
  const int colBase = blockIdx.x * 256;

  // Staging: one gload16 instruction moves one 128x32 half-tile (512 thr x 8 elem).
  // Thread t covers half-flat elems [t*8, t*8+8): row = h*128 + t/4, col = (t&3)*8.
  const int srow = tid >> 2;          // 0..127
  const int scol = (tid & 3) * 8;     // 0,8,16,24
  const size_t gA = (size_t)(rowBase + srow) * DIM + scol;
  const size_t gB = (size_t)(colBase + srow) * DIM + scol;
  const size_t HSTRIDE = (size_t)128 * DIM;

  // Fragment offsets (elements). A frag mt: row = wm*128 + mt*16 + l16, k = quad*8.
  const int aoff = (wm * 128 + l16) * 32 + quad * 8;          // + mt*512
  const int boff = B_OFF + (wn * 64 + l16) * 32 + quad * 8;   // + nt*512

  f32x4 zero = {0.f, 0.f, 0.f, 0.f};
  f32x4 acc[8][4];
#pragma unroll
  for (int mt = 0; mt < 8; ++mt)
#pragma unroll
    for (int nt = 0; nt < 4; ++nt) acc[mt][nt] = zero;

#define STAGE_A(t_) do { const size_t k_ = (size_t)(t_) * BK;                         \
    gload16(X + gA + k_,           &sbuf[(t_) & 3][A_OFF + wave * 512]);              \
    gload16(X + gA + HSTRIDE + k_, &sbuf[(t_) & 3][A_OFF + 4096 + wave * 512]);       \
  } while (0)
#define STAGE_B(t_) do { const size_t k_ = (size_t)(t_) * BK;                         \
    gload16(E + gB + k_,           &sbuf[(t_) & 3][B_OFF + wave * 512]);              \
    gload16(E + gB + HSTRIDE + k_, &sbuf[(t_) & 3][B_OFF + 4096 + wave * 512]);       \
  } while (0)

  // One K-tile = 2 fine phases. Entry: vmcnt(VM_) + barrier (tile t landed for all
  // waves). p0: read A(mt0-3)+B(all) frags || stage A half of t+3 || 16 MFMA.
  // p1: read A(mt4-7) || stage B of t+3 || 16 MFMA.  Raw barriers, no drain.
#define TILE(t_, DOSTAGE_, VM_) do {                                                  \
    asm volatile("s_waitcnt vmcnt(" #VM_ ")" ::: "memory");                           \
    __builtin_amdgcn_s_barrier();                                                     \
    __builtin_amdgcn_sched_barrier(0);                                                \
    const unsigned short* sb_ = sbuf[(t_) & 3];                                       \
    bf16x8 aL_[4], aH_[4], bF_[4];                                                    \
    _Pragma("unroll") for (int mt = 0; mt < 4; ++mt)                                  \
      aL_[mt] = *(const bf16x8*)(const void*)(sb_ + aoff + mt * 512);                 \
    _Pragma("unroll") for (int nt = 0; nt < 4; ++nt)                                  \
      bF_[nt] = *(const bf16x8*)(const void*)(sb_ + boff + nt * 512);                 \
    if (DOSTAGE_) STAGE_A((t_) + 3);                                                  \
    __builtin_amdgcn_s_setprio(1);                                                    \
    _Pragma("unroll") for (int mt = 0; mt < 4; ++mt)                                  \
      _Pragma("unroll") for (int nt = 0; nt < 4; ++nt)                                \
        acc[mt][nt] = __builtin_amdgcn_mfma_f32_16x16x32_bf16(aL_[mt], bF_[nt],       \
                                                              acc[mt][nt], 0, 0, 0);  \
    __builtin_amdgcn_s_setprio(0);                                                    \
    asm volatile("" ::: "memory");                                                    \
    __builtin_amdgcn_s_barrier();                                                     \
    __builtin_amdgcn_sched_barrier(0);                                                \
    _Pragma("unroll") for (int mt = 0; mt < 4; ++mt)                                  \
      aH_[mt] = *(const bf16x8*)(const void*)(sb_ + aoff + (mt + 4) * 512);           \
    if (DOSTAGE_) STAGE_B((t_) + 3);                                                  \
    __builtin_amdgcn_s_setprio(1);                                                    \
    _Pragma("unroll") for (int mt = 0; mt < 4; ++mt)                                  \
      _Pragma("unroll") for (int nt = 0; nt < 4; ++nt)                                \
        acc[mt + 4][nt] = __builtin_amdgcn_mfma_f32_16x16x32_bf16(aH_[mt], bF_[nt],   \
                                                              acc[mt + 4][nt], 0, 0, 0); \
    __builtin_amdgcn_s_setprio(0);                                                    \
    asm volatile("" ::: "memory");                                                    \
    __builtin_amdgcn_s_barrier();                                                     \
    __builtin_amdgcn_sched_barrier(0);                                                \
  } while (0)

  // Prologue: 3 K-tiles in flight (12 loads/thread).
  STAGE_A(0); STAGE_B(0);
  STAGE_A(1); STAGE_B(1);
  STAGE_A(2); STAGE_B(2);

  // Main: tiles 0..NT-4 stage t+3; in-flight at tile entry = 8 loads (t+1, t+2).
  for (int t = 0; t < NT - 3; ++t) {
    TILE(t, true, 8);
  }
  // Tail drain: 8 -> 4 -> 0.
  TILE(NT - 3, false, 8);
  TILE(NT - 2, false, 4);
  TILE(NT - 1, false, 0);
#undef TILE
#undef STAGE_A
#undef STAGE_B

  // Epilogue. C/D layout: col = lane&15, row = quad*4 + reg [m89/m91].
  float ec[4];
#pragma unroll
  for (int nt = 0; nt < 4; ++nt) ec[nt] = e2[colBase + wn * 64 + nt * 16 + l16];

  if (isbf) {
    unsigned short* out = (unsigned short*)outv;
#pragma unroll
    for (int mt = 0; mt < 8; ++mt)
#pragma unroll
      for (int r = 0; r < 4; ++r) {
        const int row = rowBase + wm * 128 + mt * 16 + quad * 4 + r;
        const float xr = x2[row];
#pragma unroll
        for (int nt = 0; nt < 4; ++nt) {
          const int col = colBase + wn * 64 + nt * 16 + l16;
          float sq = xr + ec[nt] - 2.0f * acc[mt][nt][r];
          sq = sq > 0.f ? sq : 0.f;
          out[(size_t)row * NGRP + col] = f2bf(-__builtin_sqrtf(sq));
        }
      }
  } else {
    float* out = (float*)outv;
#pragma unroll
    for (int mt = 0; mt < 8; ++mt)
#pragma unroll
      for (int r = 0; r < 4; ++r) {
        const int row = rowBase + wm * 128 + mt * 16 + quad * 4 + r;
        const float xr = x2[row];
#pragma unroll
        for (int nt = 0; nt < 4; ++nt) {
          const int col = colBase + wn * 64 + nt * 16 + l16;
          float sq = xr + ec[nt] - 2.0f * acc[mt][nt][r];
          sq = sq > 0.f ? sq : 0.f;
          out[(size_t)row * NGRP + col] = -__builtin_sqrtf(sq);
        }
      }
  }
}

// ---------------- fallback path (workspace too small): round-0 kernels ----------------

__global__ void sniff_kernel(const unsigned short* __restrict__ X, int* __restrict__ flag) {
  if (threadIdx.x == 0 && blockIdx.x == 0) {
    int c = 0;
    for (int i = 0; i < 64; ++i) {
      unsigned b = (X[i] >> 8) & 0x7F;
      c += (b >= 0x3B && b <= 0x41) ? 1 : 0;
    }
    *flag = (c >= 48) ? 1 : 0;
  }
}

__global__ __launch_bounds__(256) void rownorm_kernel(const void* __restrict__ in,
                                                      float* __restrict__ out,
                                                      const int* __restrict__ flag) {
  const int wave = threadIdx.x >> 6;
  const int lane = threadIdx.x & 63;
  const int row  = blockIdx.x * 4 + wave;
  float s = 0.f;
  if (*flag) {
    const unsigned short* p = (const unsigned short*)in + (size_t)row * DIM;
#pragma unroll
    for (int it = 0; it < 4; ++it) {
      uint4 v = *(const uint4*)(p + it * 512 + lane * 8);
      float f;
      f = bflo(v.x); s += f * f;  f = bfhi(v.x); s += f * f;
      f = bflo(v.y); s += f * f;  f = bfhi(v.y); s += f * f;
      f = bflo(v.z); s += f * f;  f = bfhi(v.z); s += f * f;
      f = bflo(v.w); s += f * f;  f = bfhi(v.w); s += f * f;
    }
  } else {
    const float* p = (const float*)in + (size_t)row * DIM;
#pragma unroll
    for (int it = 0; it < 4; ++it) {
      float4 a = *(const float4*)(p + it * 512 + lane * 8);
      float4 b = *(const float4*)(p + it * 512 + lane * 8 + 4);
      s += a.x * a.x + a.y * a.y + a.z * a.z + a.w * a.w;
      s += b.x * b.x + b.y * b.y + b.z * b.z + b.w * b.w;
    }
  }
#pragma unroll
  for (int off = 32; off > 0; off >>= 1) s += __shfl_down(s, off, 64);
  if (lane == 0) out[row] = s;
}

__device__ __forceinline__ u16x8 cvt8(const float* p) {
  float4 a = *(const float4*)p;
  float4 b = *(const float4*)(p + 4);
  u16x8 r;
  r[0] = f2bf(a.x); r[1] = f2bf(a.y); r[2] = f2bf(a.z); r[3] = f2bf(a.w);
  r[4] = f2bf(b.x); r[5] = f2bf(b.y); r[6] = f2bf(b.z); r[7] = f2bf(b.w);
  return r;
}

__global__ __launch_bounds__(256) void gemm_dist_kernel(
    const void* __restrict__ Xv, const void* __restrict__ Ev,
    const float* __restrict__ x2, const float* __restrict__ e2,
    void* __restrict__ outv, const int* __restrict__ flag) {
  __shared__ __align__(16) unsigned short sA[128 * 32];
  __shared__ __align__(16) unsigned short sB[128 * 32];

  const bool isbf = (*flag != 0);
  const int tid  = threadIdx.x;
  const int lane = tid & 63;
  const int wave = tid >> 6;
  const int wm   = wave >> 1;
  const int wn   = wave & 1;
  const int quad = lane >> 4;
  const int l16  = lane & 15;

  const int rowBase = blockIdx.y * 128;
  const int colBase = blockIdx.x * 128;

  const int flat0 = tid * 8;
  const int flat1 = (tid + 256) * 8;
  const int r0 = flat0 >> 5, c0 = flat0 & 31;
  const int r1 = flat1 >> 5, c1 = flat1 & 31;

  const size_t iA0 = (size_t)(rowBase + r0) * DIM + c0;
  const size_t iA1 = (size_t)(rowBase + r1) * DIM + c1;
  const size_t iB0 = (size_t)(colBase + r0) * DIM + c0;
  const size_t iB1 = (size_t)(colBase + r1) * DIM + c1;

  f32x4 zero = {0.f, 0.f, 0.f, 0.f};
  f32x4 acc[4][4];
#pragma unroll
  for (int mt = 0; mt < 4; ++mt)
#pragma unroll
    for (int nt = 0; nt < 4; ++nt) acc[mt][nt] = zero;

  for (int k0 = 0; k0 < DIM; k0 += 32) {
    if (isbf) {
      const unsigned short* X = (const unsigned short*)Xv;
      const unsigned short* E = (const unsigned short*)Ev;
      *(uint4*)(sA + flat0) = *(const uint4*)(X + iA0 + k0);
      *(uint4*)(sA + flat1) = *(const uint4*)(X + iA1 + k0);
      *(uint4*)(sB + flat0) = *(const uint4*)(E + iB0 + k0);
      *(uint4*)(sB + flat1) = *(const uint4*)(E + iB1 + k0);
    } else {
      const float* X = (const float*)Xv;
      const float* E = (const float*)Ev;
      *(u16x8*)(sA + flat0) = cvt8(X + iA0 + k0);
      *(u16x8*)(sA + flat1) = cvt8(X + iA1 + k0);
      *(u16x8*)(sB + flat0) = cvt8(E + iB0 + k0);
      *(u16x8*)(sB + flat1) = cvt8(E + iB1 + k0);
    }
    __syncthreads();

    bf16x8 a[4], b[4];
#pragma unroll
    for (int mt = 0; mt < 4; ++mt)
      a[mt] = *(const bf16x8*)(const void*)(sA + (wm * 64 + mt * 16 + l16) * 32 + quad * 8);
#pragma unroll
    for (int nt = 0; nt < 4; ++nt)
      b[nt] = *(const bf16x8*)(const void*)(sB + (wn * 64 + nt * 16 + l16) * 32 + quad * 8);
#pragma unroll
    for (int mt = 0; mt < 4; ++mt)
#pragma unroll
      for (int nt = 0; nt < 4; ++nt)
        acc[mt][nt] = __builtin_amdgcn_mfma_f32_16x16x32_bf16(a[mt], b[nt], acc[mt][nt], 0, 0, 0);
    __syncthreads();
  }

  float ec[4];
#pragma unroll
  for (int nt = 0; nt < 4; ++nt) ec[nt] = e2[colBase + wn * 64 + nt * 16 + l16];

  if (isbf) {
    unsigned short* out = (unsigned short*)outv;
#pragma unroll
    for (int mt = 0; mt < 4; ++mt)
#pragma unroll
      for (int r = 0; r < 4; ++r) {
        const int row = rowBase + wm * 64 + mt * 16 + quad * 4 + r;
        const float xr = x2[row];
#pragma unroll
        for (int nt = 0; nt < 4; ++nt) {
          const int col = colBase + wn * 64 + nt * 16 + l16;
          float sq = xr + ec[nt] - 2.0f * acc[mt][nt][r];
          sq = sq > 0.f ? sq : 0.f;
          out[(size_t)row * NGRP + col] = f2bf(-__builtin_sqrtf(sq));
        }
      }
  } else {
    float* out = (float*)outv;
#pragma unroll
    for (int mt = 0; mt < 4; ++mt)
#pragma unroll
      for (int r = 0; r < 4; ++r) {
        const int row = rowBase + wm * 64 + mt * 16 + quad * 4 + r;
        const float xr = x2[row];
#pragma unroll
        for (int nt = 0; nt < 4; ++nt) {
          const int col = colBase + wn * 64 + nt * 16 + l16;
          float sq = xr + ec[nt] - 2.0f * acc[mt][nt][r];
          sq = sq > 0.f ? sq : 0.f;
          out[(size_t)row * NGRP + col] = -__builtin_sqrtf(sq);
        }
      }
  }
}

extern "C" void kernel_launch(void* const* d_in, const int* in_sizes, int n_in,
                              void* d_out, int out_size, void* d_ws, size_t ws_size,
                              hipStream_t stream) {
  const size_t xbf = (size_t)NPTS * DIM;
  const size_t ebf = (size_t)NGRP * DIM;
  const size_t need = (xbf + ebf) * sizeof(unsigned short)
                    + (NPTS + NGRP) * sizeof(float) + 64;

  if (ws_size >= need) {
    // Fast path: fused prep (self-sniff) + 256^2 8-wave pipelined GEMM.
    unsigned short* Xbf = (unsigned short*)d_ws;
    unsigned short* Ebf = Xbf + xbf;
    float* x2 = (float*)(Ebf + ebf);
    float* e2 = x2 + NPTS;

    prep_all_kernel<<<(NPTS + NGRP) / 4, 256, 0, stream>>>(d_in[0], d_in[1],
                                                           Xbf, Ebf, x2, e2);
    dim3 grid(NGRP / 256, NPTS / 256);
    gemm_8p_kernel<<<grid, 512, 0, stream>>>(d_in[0], Xbf, d_in[1], Ebf,
                                             x2, e2, d_out);
  } else {
    // Fallback: round-0 verified path.
    float* x2 = (float*)d_ws;
    float* e2 = x2 + NPTS;
    int* flag = (int*)(e2 + NGRP);

    sniff_kernel<<<1, 64, 0, stream>>>((const unsigned short*)d_in[0], flag);
    rownorm_kernel<<<NPTS / 4, 256, 0, stream>>>(d_in[0], x2, flag);
    rownorm_kernel<<<NGRP / 4, 256, 0, stream>>>(d_in[1], e2, flag);
    dim3 grid(NGRP / 128, NPTS / 128);
    gemm_dist_kernel<<<grid, 256, 0, stream>>>(d_in[0], d_in[1], x2, e2, d_out, flag);
  }
}

// Round 4
// 623.647 us; speedup vs baseline: 1.3303x; 1.0165x over previous
//
#include <hip/hip_runtime.h>
#include <hip/hip_bf16.h>

#define NPTS 16384
#define DIM  2048
#define NGRP 4096
#define BK   32
#define NT   (DIM / BK)   // 64 K-tiles

typedef __bf16 bf16x8 __attribute__((ext_vector_type(8)));
typedef unsigned short u16x8 __attribute__((ext_vector_type(8)));
typedef float f32x4 __attribute__((ext_vector_type(4)));

__device__ __forceinline__ unsigned short f2bf(float f) {
  union { float f; unsigned u; } v; v.f = f;
  unsigned u = v.u;
  return (unsigned short)((u + 0x7FFFu + ((u >> 16) & 1u)) >> 16);  // RTNE
}
__device__ __forceinline__ float bflo(unsigned u) { return __uint_as_float(u << 16); }
__device__ __forceinline__ float bfhi(unsigned u) { return __uint_as_float(u & 0xffff0000u); }

// Async global->LDS, 16B per lane. LDS dest is wave-uniform base + lane*16.
__device__ __forceinline__ void gload16(const void* g, void* lds) {
  __builtin_amdgcn_global_load_lds(
      (const __attribute__((address_space(1))) unsigned*)g,
      (__attribute__((address_space(3))) unsigned*)lds, 16, 0, 0);
}

// Per-wave deterministic dtype sniff: all waves inspect X[0..63] -> identical verdict.
__device__ __forceinline__ bool sniff_bf16(const void* X) {
  const int lane = threadIdx.x & 63;
  unsigned hb = (((const unsigned short*)X)[lane] >> 8) & 0x7Fu;
  unsigned long long m = __ballot(hb >= 0x3Bu && hb <= 0x41u);
  return __popcll(m) >= 48;
}

// ---- fused prep: self-sniff + row norms (+ fp32->bf16 copy when fp32 input) ----
__global__ __launch_bounds__(256) void prep_all_kernel(
    const void* __restrict__ Xin, const void* __restrict__ Ein,
    unsigned short* __restrict__ Xbf, unsigned short* __restrict__ Ebf,
    float* __restrict__ x2, float* __restrict__ e2) {
  const int lane  = threadIdx.x & 63;
  const int wavei = threadIdx.x >> 6;
  const bool isbf = sniff_bf16(Xin);

  const int grow = blockIdx.x * 4 + wavei;
  const void* in; unsigned short* q; float* nrm; int row;
  if (grow < NPTS) { in = Xin; q = Xbf; nrm = x2; row = grow; }
  else             { in = Ein; q = Ebf; nrm = e2; row = grow - NPTS; }

  float s = 0.f;
  if (isbf) {
    const unsigned short* p = (const unsigned short*)in + (size_t)row * DIM;
#pragma unroll
    for (int it = 0; it < 4; ++it) {
      uint4 v = *(const uint4*)(p + it * 512 + lane * 8);
      float f;
      f = bflo(v.x); s += f * f;  f = bfhi(v.x); s += f * f;
      f = bflo(v.y); s += f * f;  f = bfhi(v.y); s += f * f;
      f = bflo(v.z); s += f * f;  f = bfhi(v.z); s += f * f;
      f = bflo(v.w); s += f * f;  f = bfhi(v.w); s += f * f;
    }
  } else {
    const float* p = (const float*)in + (size_t)row * DIM;
    unsigned short* qq = q + (size_t)row * DIM;
#pragma unroll
    for (int it = 0; it < 4; ++it) {
      float4 a = *(const float4*)(p + it * 512 + lane * 8);
      float4 b = *(const float4*)(p + it * 512 + lane * 8 + 4);
      s += a.x * a.x + a.y * a.y + a.z * a.z + a.w * a.w;
      s += b.x * b.x + b.y * b.y + b.z * b.z + b.w * b.w;
      u16x8 r;
      r[0] = f2bf(a.x); r[1] = f2bf(a.y); r[2] = f2bf(a.z); r[3] = f2bf(a.w);
      r[4] = f2bf(b.x); r[5] = f2bf(b.y); r[6] = f2bf(b.z); r[7] = f2bf(b.w);
      *(u16x8*)(qq + it * 512 + lane * 8) = r;
    }
  }
#pragma unroll
  for (int off = 32; off > 0; off >>= 1) s += __shfl_down(s, off, 64);
  if (lane == 0) nrm[row] = s;
}

// ---- 256x256 8-wave GEMM, BK=32, 4-deep circular LDS (128 KiB), 2 fine phases
//      per K-tile {stage || ds_read || 16 MFMA}, counted vmcnt(8), raw barriers,
//      setprio. XCD-chunked L2-blocked tile ordering:
//      xcd = bid&7 owns row-blocks [xcd*8, xcd*8+8); within XCD, 2-col groups x
//      8 rows, col fastest -> B-group (2 MB) L2-resident, A-panel short reuse. ----
#define A_OFF 0
#define B_OFF 8192

__global__ __launch_bounds__(512, 2) void gemm_8p_kernel(
    const void* __restrict__ Xin, const unsigned short* __restrict__ Xws,
    const void* __restrict__ Ein, const unsigned short* __restrict__ Ews,
    const float* __restrict__ x2, const float* __restrict__ e2,
    void* __restrict__ outv) {
  // 4 bufs x [ A: 256x32 | B: 256x32 ] bf16 = 4 x 32 KiB = 128 KiB
  __shared__ __align__(16) unsigned short sbuf[4][16384];

  const int tid  = threadIdx.x;
  const int lane = tid & 63;
  const int wave = tid >> 6;   // 0..7
  const int wm   = wave >> 2;  // 0..1  (M half: 128 rows)
  const int wn   = wave & 3;   // 0..3  (N quarter: 64 cols)
  const int quad = lane >> 4;
  const int l16  = lane & 15;

  const bool isbf = sniff_bf16(Xin);
  const unsigned short* X = isbf ? (const unsigned short*)Xin : Xws;
  const unsigned short* E = isbf ? (const unsigned short*)Ein : Ews;

  // XCD-chunked mapping: grid = 1024 (= 64 row-blocks x 16 col-blocks).
  // xcd = bid&7 (round-robin dispatch heuristic); local = bid>>3 in [0,128):
  // g = local>>4 (8 groups of 2 cols), r = (local>>1)&7, cg = local&1.
  const int bid   = blockIdx.x;
  const int xcd   = bid & 7;
  const int local = bid >> 3;
  const int g  = local >> 4;
  const int r  = (local >> 1) & 7;
  const int cg = local & 1;
  const int tileY = xcd * 8 + r;    // 0..63
  const int tileX = g * 2 + cg;     // 0..15

  const int rowBase = tileY * 256;
  const int colBase = tileX * 256;

  // Staging: one gload16 moves one 128x32 half-tile (512 thr x 8 elem).
  const int srow = tid >> 2;          // 0..127
  const int scol = (tid & 3) * 8;     // 0,8,16,24
  const size_t gA = (size_t)(rowBase + srow) * DIM + scol;
  const size_t gB = (size_t)(colBase + srow) * DIM + scol;
  const size_t HSTRIDE = (size_t)128 * DIM;

  // Fragment offsets (elements). A frag mt: row = wm*128 + mt*16 + l16, k = quad*8.
  const int aoff = (wm * 128 + l16) * 32 + quad * 8;          // + mt*512
  const int boff = B_OFF + (wn * 64 + l16) * 32 + quad * 8;   // + nt*512

  f32x4 zero = {0.f, 0.f, 0.f, 0.f};
  f32x4 acc[8][4];
#pragma unroll
  for (int mt = 0; mt < 8; ++mt)
#pragma unroll
    for (int nt = 0; nt < 4; ++nt) acc[mt][nt] = zero;

#define STAGE_A(t_) do { const size_t k_ = (size_t)(t_) * BK;                         \
    gload16(X + gA + k_,           &sbuf[(t_) & 3][A_OFF + wave * 512]);              \
    gload16(X + gA + HSTRIDE + k_, &sbuf[(t_) & 3][A_OFF + 4096 + wave * 512]);       \
  } while (0)
#define STAGE_B(t_) do { const size_t k_ = (size_t)(t_) * BK;                         \
    gload16(E + gB + k_,           &sbuf[(t_) & 3][B_OFF + wave * 512]);              \
    gload16(E + gB + HSTRIDE + k_, &sbuf[(t_) & 3][B_OFF + 4096 + wave * 512]);       \
  } while (0)

  // One K-tile = 2 fine phases. Entry: vmcnt(VM_) + barrier (tile t landed for all
  // waves). p0: stage A of t+3 || read A(mt0-3)+B frags || 16 MFMA.
  // p1: stage B of t+3 || read A(mt4-7) || 16 MFMA.  Raw barriers, no drain.
  // Buffer safety: STAGE(t+3) writes buf[(t+3)&3] = buf[(t-1)&3]; all waves
  // finished reading it before tile t's entry barrier.
#define TILE(t_, DOSTAGE_, VM_) do {                                                  \
    asm volatile("s_waitcnt vmcnt(" #VM_ ")" ::: "memory");                           \
    __builtin_amdgcn_s_barrier();                                                     \
    __builtin_amdgcn_sched_barrier(0);                                                \
    const unsigned short* sb_ = sbuf[(t_) & 3];                                       \
    bf16x8 aL_[4], aH_[4], bF_[4];                                                    \
    if (DOSTAGE_) STAGE_A((t_) + 3);                                                  \
    _Pragma("unroll") for (int mt = 0; mt < 4; ++mt)                                  \
      aL_[mt] = *(const bf16x8*)(const void*)(sb_ + aoff + mt * 512);                 \
    _Pragma("unroll") for (int nt = 0; nt < 4; ++nt)                                  \
      bF_[nt] = *(const bf16x8*)(const void*)(sb_ + boff + nt * 512);                 \
    __builtin_amdgcn_s_setprio(1);                                                    \
    _Pragma("unroll") for (int mt = 0; mt < 4; ++mt)                                  \
      _Pragma("unroll") for (int nt = 0; nt < 4; ++nt)                                \
        acc[mt][nt] = __builtin_amdgcn_mfma_f32_16x16x32_bf16(aL_[mt], bF_[nt],       \
                                                              acc[mt][nt], 0, 0, 0);  \
    __builtin_amdgcn_s_setprio(0);                                                    \
    asm volatile("" ::: "memory");                                                    \
    __builtin_amdgcn_s_barrier();                                                     \
    __builtin_amdgcn_sched_barrier(0);                                                \
    if (DOSTAGE_) STAGE_B((t_) + 3);                                                  \
    _Pragma("unroll") for (int mt = 0; mt < 4; ++mt)                                  \
      aH_[mt] = *(const bf16x8*)(const void*)(sb_ + aoff + (mt + 4) * 512);           \
    __builtin_amdgcn_s_setprio(1);                                                    \
    _Pragma("unroll") for (int mt = 0; mt < 4; ++mt)                                  \
      _Pragma("unroll") for (int nt = 0; nt < 4; ++nt)                                \
        acc[mt + 4][nt] = __builtin_amdgcn_mfma_f32_16x16x32_bf16(aH_[mt], bF_[nt],   \
                                                              acc[mt + 4][nt], 0, 0, 0); \
    __builtin_amdgcn_s_setprio(0);                                                    \
    asm volatile("" ::: "memory");                                                    \
    __builtin_amdgcn_s_barrier();                                                     \
    __builtin_amdgcn_sched_barrier(0);                                                \
  } while (0)

  // Prologue: 3 K-tiles in flight (12 loads/thread).
  STAGE_A(0); STAGE_B(0);
  STAGE_A(1); STAGE_B(1);
  STAGE_A(2); STAGE_B(2);

  // Main: tiles 0..NT-4 stage t+3; in-flight at tile entry = 8 loads (t+1, t+2).
  for (int t = 0; t < NT - 3; ++t) {
    TILE(t, true, 8);
  }
  // Tail drain: 8 -> 4 -> 0.
  TILE(NT - 3, false, 8);
  TILE(NT - 2, false, 4);
  TILE(NT - 1, false, 0);
#undef TILE
#undef STAGE_A
#undef STAGE_B

  // Epilogue. C/D layout: col = lane&15, row = quad*4 + reg [m89/m91].
  float ec[4];
#pragma unroll
  for (int nt = 0; nt < 4; ++nt) ec[nt] = e2[colBase + wn * 64 + nt * 16 + l16];

  if (isbf) {
    unsigned short* out = (unsigned short*)outv;
#pragma unroll
    for (int mt = 0; mt < 8; ++mt)
#pragma unroll
      for (int r2 = 0; r2 < 4; ++r2) {
        const int row = rowBase + wm * 128 + mt * 16 + quad * 4 + r2;
        const float xr = x2[row];
#pragma unroll
        for (int nt = 0; nt < 4; ++nt) {
          const int col = colBase + wn * 64 + nt * 16 + l16;
          float sq = xr + ec[nt] - 2.0f * acc[mt][nt][r2];
          sq = sq > 0.f ? sq : 0.f;
          out[(size_t)row * NGRP + col] = f2bf(-__builtin_sqrtf(sq));
        }
      }
  } else {
    float* out = (float*)outv;
#pragma unroll
    for (int mt = 0; mt < 8; ++mt)
#pragma unroll
      for (int r2 = 0; r2 < 4; ++r2) {
        const int row = rowBase + wm * 128 + mt * 16 + quad * 4 + r2;
        const float xr = x2[row];
#pragma unroll
        for (int nt = 0; nt < 4; ++nt) {
          const int col = colBase + wn * 64 + nt * 16 + l16;
          float sq = xr + ec[nt] - 2.0f * acc[mt][nt][r2];
          sq = sq > 0.f ? sq : 0.f;
          out[(size_t)row * NGRP + col] = -__builtin_sqrtf(sq);
        }
      }
  }
}

// ---------------- fallback path (workspace too small): round-0 kernels ----------------

__global__ void sniff_kernel(const unsigned short* __restrict__ X, int* __restrict__ flag) {
  if (threadIdx.x == 0 && blockIdx.x == 0) {
    int c = 0;
    for (int i = 0; i < 64; ++i) {
      unsigned b = (X[i] >> 8) & 0x7F;
      c += (b >= 0x3B && b <= 0x41) ? 1 : 0;
    }
    *flag = (c >= 48) ? 1 : 0;
  }
}

__global__ __launch_bounds__(256) void rownorm_kernel(const void* __restrict__ in,
                                                      float* __restrict__ out,
                                                      const int* __restrict__ flag) {
  const int wave = threadIdx.x >> 6;
  const int lane = threadIdx.x & 63;
  const int row  = blockIdx.x * 4 + wave;
  float s = 0.f;
  if (*flag) {
    const unsigned short* p = (const unsigned short*)in + (size_t)row * DIM;
#pragma unroll
    for (int it = 0; it < 4; ++it) {
      uint4 v = *(const uint4*)(p + it * 512 + lane * 8);
      float f;
      f = bflo(v.x); s += f * f;  f = bfhi(v.x); s += f * f;
      f = bflo(v.y); s += f * f;  f = bfhi(v.y); s += f * f;
      f = bflo(v.z); s += f * f;  f = bfhi(v.z); s += f * f;
      f = bflo(v.w); s += f * f;  f = bfhi(v.w); s += f * f;
    }
  } else {
    const float* p = (const float*)in + (size_t)row * DIM;
#pragma unroll
    for (int it = 0; it < 4; ++it) {
      float4 a = *(const float4*)(p + it * 512 + lane * 8);
      float4 b = *(const float4*)(p + it * 512 + lane * 8 + 4);
      s += a.x * a.x + a.y * a.y + a.z * a.z + a.w * a.w;
      s += b.x * b.x + b.y * b.y + b.z * b.z + b.w * b.w;
    }
  }
#pragma unroll
  for (int off = 32; off > 0; off >>= 1) s += __shfl_down(s, off, 64);
  if (lane == 0) out[row] = s;
}

__device__ __forceinline__ u16x8 cvt8(const float* p) {
  float4 a = *(const float4*)p;
  float4 b = *(const float4*)(p + 4);
  u16x8 r;
  r[0] = f2bf(a.x); r[1] = f2bf(a.y); r[2] = f2bf(a.z); r[3] = f2bf(a.w);
  r[4] = f2bf(b.x); r[5] = f2bf(b.y); r[6] = f2bf(b.z); r[7] = f2bf(b.w);
  return r;
}

__global__ __launch_bounds__(256) void gemm_dist_kernel(
    const void* __restrict__ Xv, const void* __restrict__ Ev,
    const float* __restrict__ x2, const float* __restrict__ e2,
    void* __restrict__ outv, const int* __restrict__ flag) {
  __shared__ __align__(16) unsigned short sA[128 * 32];
  __shared__ __align__(16) unsigned short sB[128 * 32];

  const bool isbf = (*flag != 0);
  const int tid  = threadIdx.x;
  const int lane = tid & 63;
  const int wave = tid >> 6;
  const int wm   = wave >> 1;
  const int wn   = wave & 1;
  const int quad = lane >> 4;
  const int l16  = lane & 15;

  const int rowBase = blockIdx.y * 128;
  const int colBase = blockIdx.x * 128;

  const int flat0 = tid * 8;
  const int flat1 = (tid + 256) * 8;
  const int r0 = flat0 >> 5, c0 = flat0 & 31;
  const int r1 = flat1 >> 5, c1 = flat1 & 31;

  const size_t iA0 = (size_t)(rowBase + r0) * DIM + c0;
  const size_t iA1 = (size_t)(rowBase + r1) * DIM + c1;
  const size_t iB0 = (size_t)(colBase + r0) * DIM + c0;
  const size_t iB1 = (size_t)(colBase + r1) * DIM + c1;

  f32x4 zero = {0.f, 0.f, 0.f, 0.f};
  f32x4 acc[4][4];
#pragma unroll
  for (int mt = 0; mt < 4; ++mt)
#pragma unroll
    for (int nt = 0; nt < 4; ++nt) acc[mt][nt] = zero;

  for (int k0 = 0; k0 < DIM; k0 += 32) {
    if (isbf) {
      const unsigned short* X = (const unsigned short*)Xv;
      const unsigned short* E = (const unsigned short*)Ev;
      *(uint4*)(sA + flat0) = *(const uint4*)(X + iA0 + k0);
      *(uint4*)(sA + flat1) = *(const uint4*)(X + iA1 + k0);
      *(uint4*)(sB + flat0) = *(const uint4*)(E + iB0 + k0);
      *(uint4*)(sB + flat1) = *(const uint4*)(E + iB1 + k0);
    } else {
      const float* X = (const float*)Xv;
      const float* E = (const float*)Ev;
      *(u16x8*)(sA + flat0) = cvt8(X + iA0 + k0);
      *(u16x8*)(sA + flat1) = cvt8(X + iA1 + k0);
      *(u16x8*)(sB + flat0) = cvt8(E + iB0 + k0);
      *(u16x8*)(sB + flat1) = cvt8(E + iB1 + k0);
    }
    __syncthreads();

    bf16x8 a[4], b[4];
#pragma unroll
    for (int mt = 0; mt < 4; ++mt)
      a[mt] = *(const bf16x8*)(const void*)(sA + (wm * 64 + mt * 16 + l16) * 32 + quad * 8);
#pragma unroll
    for (int nt = 0; nt < 4; ++nt)
      b[nt] = *(const bf16x8*)(const void*)(sB + (wn * 64 + nt * 16 + l16) * 32 + quad * 8);
#pragma unroll
    for (int mt = 0; mt < 4; ++mt)
#pragma unroll
      for (int nt = 0; nt < 4; ++nt)
        acc[mt][nt] = __builtin_amdgcn_mfma_f32_16x16x32_bf16(a[mt], b[nt], acc[mt][nt], 0, 0, 0);
    __syncthreads();
  }

  float ec[4];
#pragma unroll
  for (int nt = 0; nt < 4; ++nt) ec[nt] = e2[colBase + wn * 64 + nt * 16 + l16];

  if (isbf) {
    unsigned short* out = (unsigned short*)outv;
#pragma unroll
    for (int mt = 0; mt < 4; ++mt)
#pragma unroll
      for (int r = 0; r < 4; ++r) {
        const int row = rowBase + wm * 64 + mt * 16 + quad * 4 + r;
        const float xr = x2[row];
#pragma unroll
        for (int nt = 0; nt < 4; ++nt) {
          const int col = colBase + wn * 64 + nt * 16 + l16;
          float sq = xr + ec[nt] - 2.0f * acc[mt][nt][r];
          sq = sq > 0.f ? sq : 0.f;
          out[(size_t)row * NGRP + col] = f2bf(-__builtin_sqrtf(sq));
        }
      }
  } else {
    float* out = (float*)outv;
#pragma unroll
    for (int mt = 0; mt < 4; ++mt)
#pragma unroll
      for (int r = 0; r < 4; ++r) {
        const int row = rowBase + wm * 64 + mt * 16 + quad * 4 + r;
        const float xr = x2[row];
#pragma unroll
        for (int nt = 0; nt < 4; ++nt) {
          const int col = colBase + wn * 64 + nt * 16 + l16;
          float sq = xr + ec[nt] - 2.0f * acc[mt][nt][r];
          sq = sq > 0.f ? sq : 0.f;
          out[(size_t)row * NGRP + col] = -__builtin_sqrtf(sq);
        }
      }
  }
}

extern "C" void kernel_launch(void* const* d_in, const int* in_sizes, int n_in,
                              void* d_out, int out_size, void* d_ws, size_t ws_size,
                              hipStream_t stream) {
  const size_t xbf = (size_t)NPTS * DIM;
  const size_t ebf = (size_t)NGRP * DIM;
  const size_t need = (xbf + ebf) * sizeof(unsigned short)
                    + (NPTS + NGRP) * sizeof(float) + 64;

  if (ws_size >= need) {
    // Fast path: fused prep (self-sniff) + 256^2 8-wave pipelined GEMM,
    // XCD-chunked L2-blocked 1D grid.
    unsigned short* Xbf = (unsigned short*)d_ws;
    unsigned short* Ebf = Xbf + xbf;
    float* x2 = (float*)(Ebf + ebf);
    float* e2 = x2 + NPTS;

    prep_all_kernel<<<(NPTS + NGRP) / 4, 256, 0, stream>>>(d_in[0], d_in[1],
                                                           Xbf, Ebf, x2, e2);
    gemm_8p_kernel<<<(NPTS / 256) * (NGRP / 256), 512, 0, stream>>>(
        d_in[0], Xbf, d_in[1], Ebf, x2, e2, d_out);
  } else {
    // Fallback: round-0 verified path.
    float* x2 = (float*)d_ws;
    float* e2 = x2 + NPTS;
    int* flag = (int*)(e2 + NGRP);

    sniff_kernel<<<1, 64, 0, stream>>>((const unsigned short*)d_in[0], flag);
    rownorm_kernel<<<NPTS / 4, 256, 0, stream>>>(d_in[0], x2, flag);
    rownorm_kernel<<<NGRP / 4, 256, 0, stream>>>(d_in[1], e2, flag);
    dim3 grid(NGRP / 128, NPTS / 128);
    gemm_dist_kernel<<<grid, 256, 0, stream>>>(d_in[0], d_in[1], x2, e2, d_out, flag);
  }
}